// Round 1
// baseline (321.324 us; speedup 1.0000x reference)
//
#include <hip/hip_runtime.h>

#define N_BITS   64
#define N_GROUPS 8
#define PDIM     8
#define MAX_TABLE 32768
#define BATCH    524288

// One thread per (batch element, group). 8 threads/element, consecutive lanes.
__global__ __launch_bounds__(256) void comp_mapper_kernel(
    const int*   __restrict__ bits,   // (BATCH, 64) 0/1 int32
    const float* __restrict__ gt,     // (8, 8, 32768) fp32
    const int*   __restrict__ ct,     // (7, 256) 0/1 int32
    float*       __restrict__ out)    // (BATCH, 64) fp32
{
    const int tid = blockIdx.x * blockDim.x + threadIdx.x;   // 0 .. BATCH*8-1
    const int g   = tid & 7;

    // --- load this group's 8 bits (32 contiguous bytes per thread) ---
    const int4* bp = reinterpret_cast<const int4*>(bits) + (size_t)tid * 2;
    int4 x = bp[0];
    int4 y = bp[1];

    // gaddr: bit j (j=0 first) has weight 2^(7-j)
    int gaddr = (x.x << 7) | (x.y << 6) | (x.z << 5) | (x.w << 4)
              | (y.x << 3) | (y.y << 2) | (y.z << 1) |  y.w;

    // --- per-group carry (groups 0..6 only) ---
    int carry = 0;
    if (g < 7) carry = ct[g * 256 + gaddr];

    // --- exchange carries across the element's 8 lanes via ballot ---
    unsigned long long m = __ballot(carry);
    const int lane = threadIdx.x & 63;
    const int base = lane & ~7;                       // element's lane-0
    unsigned f = (unsigned)((m >> base) & 0xFFull);   // bit j = carry of group j
    // v = sum_{j<g} c_j * 2^(g-1-j)  ==  brev8(f) >> (8-g)   (g=0 -> 0)
    unsigned v = (__brev(f) >> 24) >> (8 - g);

    const int addr = (gaddr << g) | (int)v;           // < 2^(8+g) <= 32768

    // --- 8 gathers from this group's table rows (L2/L3-resident) ---
    const float* t = gt + (size_t)g * (PDIM * MAX_TABLE) + addr;
    float4 o0, o1;
    o0.x = t[0 * MAX_TABLE];
    o0.y = t[1 * MAX_TABLE];
    o0.z = t[2 * MAX_TABLE];
    o0.w = t[3 * MAX_TABLE];
    o1.x = t[4 * MAX_TABLE];
    o1.y = t[5 * MAX_TABLE];
    o1.z = t[6 * MAX_TABLE];
    o1.w = t[7 * MAX_TABLE];

    // --- coalesced store: 32 contiguous bytes per thread ---
    float4* op = reinterpret_cast<float4*>(out) + (size_t)tid * 2;
    op[0] = o0;
    op[1] = o1;
}

extern "C" void kernel_launch(void* const* d_in, const int* in_sizes, int n_in,
                              void* d_out, int out_size, void* d_ws, size_t ws_size,
                              hipStream_t stream) {
    const int*   bits = (const int*)  d_in[0];
    const float* gt   = (const float*)d_in[1];
    const int*   ct   = (const int*)  d_in[2];
    float*       out  = (float*)      d_out;

    const int total_threads = BATCH * N_GROUPS;       // 4,194,304
    const int block = 256;
    const int grid  = total_threads / block;          // 16384

    comp_mapper_kernel<<<grid, block, 0, stream>>>(bits, gt, ct, out);
}

// Round 2
// 273.721 us; speedup vs baseline: 1.1739x; 1.1739x over previous
//
#include <hip/hip_runtime.h>

#define N_BITS    64
#define N_GROUPS  8
#define PDIM      8
#define MAX_TABLE 32768
#define BATCH     524288

// ---------------------------------------------------------------------------
// Pass 1: transpose group_tables (8, 8, 32768) -> tt (8, 32768, 8) so the 8
// p-values for one addr are contiguous (32 B, 32 B-aligned => single 64 B line).
// ---------------------------------------------------------------------------
__global__ __launch_bounds__(256) void transpose_tables(
    const float* __restrict__ gt,   // (8, 8, 32768)
    float*       __restrict__ tt)   // (8, 32768, 8)
{
    const int i  = blockIdx.x * blockDim.x + threadIdx.x;   // 0 .. 524287
    const int a4 = i & (MAX_TABLE / 4 - 1);                 // addr/4 within row
    const int gp = i >> 13;                                 // 0..63
    const int p  = gp & 7;
    const int g  = gp >> 3;

    const float4 v = reinterpret_cast<const float4*>(gt)[i];  // coalesced
    const int a = a4 * 4;
    float* base = tt + (size_t)g * MAX_TABLE * PDIM + p;
    base[(size_t)(a + 0) * PDIM] = v.x;
    base[(size_t)(a + 1) * PDIM] = v.y;
    base[(size_t)(a + 2) * PDIM] = v.z;
    base[(size_t)(a + 3) * PDIM] = v.w;
}

// ---------------------------------------------------------------------------
// Pass 2: one thread per (batch element, group); 8 consecutive lanes = element.
// ---------------------------------------------------------------------------
template <bool TRANSPOSED>
__global__ __launch_bounds__(256) void comp_mapper_kernel(
    const int*   __restrict__ bits,   // (BATCH, 64) 0/1 int32
    const float* __restrict__ tab,    // TRANSPOSED ? (8,32768,8) : (8,8,32768)
    const int*   __restrict__ ct,     // (7, 256) 0/1 int32
    float*       __restrict__ out)    // (BATCH, 64) fp32
{
    const int tid = blockIdx.x * blockDim.x + threadIdx.x;   // 0 .. BATCH*8-1
    const int g   = tid & 7;

    // load this group's 8 bits (32 contiguous bytes per thread)
    const int4* bp = reinterpret_cast<const int4*>(bits) + (size_t)tid * 2;
    int4 x = bp[0];
    int4 y = bp[1];

    // gaddr: bit j (j=0 first) has weight 2^(7-j)
    int gaddr = (x.x << 7) | (x.y << 6) | (x.z << 5) | (x.w << 4)
              | (y.x << 3) | (y.y << 2) | (y.z << 1) |  y.w;

    // per-group carry (groups 0..6 only)
    int carry = 0;
    if (g < 7) carry = ct[g * 256 + gaddr];

    // exchange carries across the element's 8 lanes via ballot
    unsigned long long m = __ballot(carry);
    const int lane = threadIdx.x & 63;
    const int base = lane & ~7;                       // element's lane-0
    unsigned f = (unsigned)((m >> base) & 0xFFull);   // bit j = carry of group j
    // v = sum_{j<g} c_j * 2^(g-1-j)  ==  brev8(f) >> (8-g)   (g=0 -> 0)
    unsigned v = (__brev(f) >> 24) >> (8 - g);

    const int addr = (gaddr << g) | (int)v;           // < 2^(8+g) <= 32768

    float4 o0, o1;
    if (TRANSPOSED) {
        // 32 contiguous, 32B-aligned bytes: exactly one 64B line per thread
        const float4* t = reinterpret_cast<const float4*>(
            tab + ((size_t)g * MAX_TABLE + addr) * PDIM);
        o0 = t[0];
        o1 = t[1];
    } else {
        const float* t = tab + (size_t)g * (PDIM * MAX_TABLE) + addr;
        o0.x = t[0 * MAX_TABLE]; o0.y = t[1 * MAX_TABLE];
        o0.z = t[2 * MAX_TABLE]; o0.w = t[3 * MAX_TABLE];
        o1.x = t[4 * MAX_TABLE]; o1.y = t[5 * MAX_TABLE];
        o1.z = t[6 * MAX_TABLE]; o1.w = t[7 * MAX_TABLE];
    }

    // coalesced store: 32 contiguous bytes per thread
    float4* op = reinterpret_cast<float4*>(out) + (size_t)tid * 2;
    op[0] = o0;
    op[1] = o1;
}

extern "C" void kernel_launch(void* const* d_in, const int* in_sizes, int n_in,
                              void* d_out, int out_size, void* d_ws, size_t ws_size,
                              hipStream_t stream) {
    const int*   bits = (const int*)  d_in[0];
    const float* gt   = (const float*)d_in[1];
    const int*   ct   = (const int*)  d_in[2];
    float*       out  = (float*)      d_out;

    const int total_threads = BATCH * N_GROUPS;       // 4,194,304
    const int block = 256;
    const int grid  = total_threads / block;          // 16384

    const size_t tt_bytes = (size_t)N_GROUPS * MAX_TABLE * PDIM * sizeof(float); // 8 MiB

    if (ws_size >= tt_bytes) {
        float* tt = (float*)d_ws;
        const int t_threads = N_GROUPS * PDIM * MAX_TABLE / 4;   // 524288
        transpose_tables<<<t_threads / block, block, 0, stream>>>(gt, tt);
        comp_mapper_kernel<true><<<grid, block, 0, stream>>>(bits, tt, ct, out);
    } else {
        comp_mapper_kernel<false><<<grid, block, 0, stream>>>(bits, gt, ct, out);
    }
}